// Round 10
// baseline (49.587 us; speedup 1.0000x reference)
//
#include <hip/hip_runtime.h>
#include <stdint.h>

#define B_SZ 2048
#define F_SZ 24
#define E_SZ 128
#define P_SZ 276            // F*(F-1)/2
#define BT   256            // batch rows per block (8 waves x 32 cols)
#define NWG  (P_SZ * 8)     // 2208 (8 same-pair blocks -> one per XCD)

#define XT_ELEMS (B_SZ * F_SZ * E_SZ)   // 6,291,456 (12.6 MB bf16)
#define KB_ELEMS (P_SZ * E_SZ * E_SZ)   // 4,521,984 ( 9.0 MB bf16)
#define WS_NEED  ((size_t)(XT_ELEMS + KB_ELEMS) * 2)   // 21.6 MB

#define XPREP_BLKS (F_SZ * 64)          // 1536  (one per (f, 32-row group))
#define KPREP_BLKS (KB_ELEMS / 2048)    // 2208

typedef __bf16 bf16x8 __attribute__((ext_vector_type(8)));
typedef __bf16 bf16x4 __attribute__((ext_vector_type(4)));
typedef float  f32x16 __attribute__((ext_vector_type(16)));

// ---- prepack ----------------------------------------------------------------
// xft[f][grp<64][slot<512][8]: slot s holds
//   x[grp*32 + (s&31)][f][(s>>6)*16 + ((s>>5)&1)*8 + i]   (bf16)
// -> serves BOTH the MFMA B-fragments (slot = kk*64 + lane) AND the epilogue
//    Xq reads (slot = (2mt+(q>>1))*64 + (q&1)*32 + l31, elem hi*4+i), each
//    fully coalesced. No separate xqt array.
// kb[p][d][slot]: pre-XOR-swizzled K so a linear LDS DMA lands swizzled.
__global__ __launch_bounds__(256) void prepack_all(
    const float* __restrict__ x, const float* __restrict__ kern,
    __bf16* __restrict__ xft, __bf16* __restrict__ kb)
{
    const int bid = blockIdx.x;
    const int tid = threadIdx.x;
    if (bid < XPREP_BLKS) {
        const int f = bid >> 6, grp = bid & 63;
        const float* srcb = x + ((size_t)grp * 32 * F_SZ + f) * E_SZ;
        __bf16* dst = xft + (size_t)(f * 64 + grp) * 4096;
#pragma unroll
        for (int u = 0; u < 2; ++u) {
            const int s = tid * 2 + u;              // slot 0..511
            const int row = s & 31;
            const int e0  = (s >> 6) * 16 + ((s >> 5) & 1) * 8;
            const float* src = srcb + (size_t)row * (F_SZ * E_SZ) + e0;
            float4 v0 = *(const float4*)src;
            float4 v1 = *(const float4*)(src + 4);
            bf16x8 h;
            h[0] = (__bf16)v0.x; h[1] = (__bf16)v0.y; h[2] = (__bf16)v0.z; h[3] = (__bf16)v0.w;
            h[4] = (__bf16)v1.x; h[5] = (__bf16)v1.y; h[6] = (__bf16)v1.z; h[7] = (__bf16)v1.w;
            *(bf16x8*)(dst + s * 8) = h;
        }
    } else {
        int g = (bid - XPREP_BLKS) * 256 + tid;     // 16B-slot id
        int p = g >> 11, r = g & 2047;
        int d = r >> 4, s = r & 15;
        const float* src = kern + ((size_t)d * P_SZ + p) * E_SZ + ((s ^ (d & 15)) << 3);
        float4 v0 = *(const float4*)src;
        float4 v1 = *(const float4*)(src + 4);
        bf16x8 h;
        h[0] = (__bf16)v0.x; h[1] = (__bf16)v0.y; h[2] = (__bf16)v0.z; h[3] = (__bf16)v0.w;
        h[4] = (__bf16)v1.x; h[5] = (__bf16)v1.y; h[6] = (__bf16)v1.z; h[7] = (__bf16)v1.w;
        *(bf16x8*)(kb + (size_t)g * 8) = h;
    }
}

// ---- main: one block = (pair p, 256-row batch tile).
//      K_p: 32KB NT-flagged DMA (doesn't pollute L2 -> x slices stay hot).
//      Xp frags + Xq values: 24 coalesced register loads, ALL issued before
//      the barrier so their latency hides under the DMA drain.
//      Per-mt accumulator keeps VGPR ~100 -> 2 blocks/CU at (512,4).
__global__ __launch_bounds__(512, 4) void opn_main(
    const __bf16* __restrict__ xft, const __bf16* __restrict__ kb,
    float* __restrict__ out)
{
    __shared__ short sK[E_SZ * E_SZ];   // 32 KB swizzled K_p

    const int tid = threadIdx.x, w = tid >> 6, lane = tid & 63;
    const int l31 = lane & 31, hi = lane >> 5;
    const int orig = blockIdx.x;
    const int bb = orig & 7;            // batch tile = XCD (round-robin)
    const int p  = orig >> 3;           // 0..275

    int fp = 0, rem = p;
    while (rem >= F_SZ - 1 - fp) { rem -= F_SZ - 1 - fp; ++fp; }
    const int fq = fp + 1 + rem;

    // K_p DMA: linear copy of pre-swizzled image, NT policy (aux=2)
    const __bf16* kp = kb + (size_t)p * (E_SZ * E_SZ);
#pragma unroll
    for (int t = 0; t < 4; ++t) {
        const int base = (w * 4 + t) * 64;
        __builtin_amdgcn_global_load_lds(
            (const __attribute__((address_space(1))) void*)(kp + (size_t)(base + lane) * 8),
            (__attribute__((address_space(3))) void*)(&sK[base * 8]),
            16, 0, 2 /*NT*/);
    }

    const int grp = bb * 8 + w;         // this wave's 32-row batch group
    // Xp MFMA B-fragments: 8 coalesced dwordx4
    bf16x8 xpf[8];
    const __bf16* xpb = xft + (size_t)(fp * 64 + grp) * 4096 + lane * 8;
#pragma unroll
    for (int kk = 0; kk < 8; ++kk)
        xpf[kk] = *(const bf16x8*)(xpb + kk * 512);
    // Xq from xft: 16 coalesced 8B loads (512B/wave each).
    // lane (l31,hi), (mt,q) -> d = 32mt+8q+4hi+i  at slot (2mt+(q>>1))*64
    // + (q&1)*32 + l31, elem hi*4+i.
    bf16x4 xqr[4][4];
    const __bf16* xqb = xft + (size_t)(fq * 64 + grp) * 4096 + l31 * 8 + hi * 4;
#pragma unroll
    for (int mt = 0; mt < 4; ++mt)
#pragma unroll
        for (int q = 0; q < 4; ++q)
            xqr[mt][q] = *(const bf16x4*)(xqb + (mt * 2 + (q >> 1)) * 512 + (q & 1) * 256);

    __syncthreads();                    // drains K DMA (x loads done by then)

    // Per-mt: 8 chained MFMAs then immediate lane-local dot with Xq.
    // D layout: col = lane&31 (= b), row(d) = (j&3) + 8*(j>>2) + 4*hi + 32mt
    float s0 = 0.f, s1 = 0.f;
#pragma unroll
    for (int mt = 0; mt < 4; ++mt) {
        f32x16 acc;
#pragma unroll
        for (int q = 0; q < 16; ++q) acc[q] = 0.f;
        const int arow = mt * 32 + l31;
        const short* kRow = &sK[arow * E_SZ];
        const int asw = (arow & 15) << 3;
#pragma unroll
        for (int kk = 0; kk < 8; ++kk) {
            bf16x8 afr = *(const bf16x8*)&kRow[((kk * 2 + hi) << 3) ^ asw];
            acc = __builtin_amdgcn_mfma_f32_32x32x16_bf16(afr, xpf[kk], acc, 0, 0, 0);
        }
#pragma unroll
        for (int q = 0; q < 4; ++q) {
            const bf16x4 xq = xqr[mt][q];
            s0 += acc[q * 4 + 0] * (float)xq[0] + acc[q * 4 + 1] * (float)xq[1];
            s1 += acc[q * 4 + 2] * (float)xq[2] + acc[q * 4 + 3] * (float)xq[3];
        }
    }
    float s = s0 + s1;
    s += __shfl_xor(s, 32);             // combine the two hi row-groups
    if (hi == 0)
        out[(size_t)(grp * 32 + l31) * P_SZ + p] = s;
}

// ---------------- fallback (round-2 kernel, used if ws too small) -----------
__global__ __launch_bounds__(512, 4) void opn_fallback(
    const float* __restrict__ x, const float* __restrict__ kern,
    float* __restrict__ out)
{
    __shared__ short sA[128 * E_SZ];
    __shared__ short sB[E_SZ * E_SZ];
    __shared__ float red[2][128];

    const int tid = threadIdx.x;
    const int orig = blockIdx.x;
    const int nwg2 = P_SZ * 16;
    const int wgid = (orig & 7) * (nwg2 / 8) + (orig >> 3);
    const int p  = wgid >> 4;
    const int bb = wgid & 15;
    const int b0 = bb * 128;

    int fp = 0, rem = p;
    while (rem >= F_SZ - 1 - fp) { rem -= F_SZ - 1 - fp; ++fp; }
    const int fq = fp + 1 + rem;

#pragma unroll
    for (int k = 0; k < 4; ++k) {
        int i = tid + k * 512;
        int r = i >> 4, s8 = i & 15;
        const float* src = x + ((size_t)(b0 + r) * F_SZ + fp) * E_SZ + s8 * 8;
        float4 v0 = *(const float4*)src;
        float4 v1 = *(const float4*)(src + 4);
        bf16x8 h;
        h[0] = (__bf16)v0.x; h[1] = (__bf16)v0.y; h[2] = (__bf16)v0.z; h[3] = (__bf16)v0.w;
        h[4] = (__bf16)v1.x; h[5] = (__bf16)v1.y; h[6] = (__bf16)v1.z; h[7] = (__bf16)v1.w;
        *(bf16x8*)&sA[r * E_SZ + ((s8 ^ (r & 15)) << 3)] = h;
    }
#pragma unroll
    for (int k = 0; k < 4; ++k) {
        int i = tid + k * 512;
        int r = i >> 4, s8 = i & 15;
        const float* src = kern + ((size_t)r * P_SZ + p) * E_SZ + s8 * 8;
        float4 v0 = *(const float4*)src;
        float4 v1 = *(const float4*)(src + 4);
        bf16x8 h;
        h[0] = (__bf16)v0.x; h[1] = (__bf16)v0.y; h[2] = (__bf16)v0.z; h[3] = (__bf16)v0.w;
        h[4] = (__bf16)v1.x; h[5] = (__bf16)v1.y; h[6] = (__bf16)v1.z; h[7] = (__bf16)v1.w;
        *(bf16x8*)&sB[r * E_SZ + ((s8 ^ (r & 15)) << 3)] = h;
    }
    __syncthreads();

    const int w = tid >> 6, lane = tid & 63;
    const int l31 = lane & 31, hi = lane >> 5;
    const int mh = w >> 2, ng = w & 3;

    f32x16 acc[2];
#pragma unroll
    for (int mt = 0; mt < 2; ++mt)
#pragma unroll
        for (int j = 0; j < 16; ++j) acc[mt][j] = 0.f;

    const int brow = ng * 32 + l31;
#pragma unroll
    for (int kk = 0; kk < 8; ++kk) {
        const int e8 = kk * 2 + hi;
        bf16x8 bfr = *(const bf16x8*)&sA[brow * E_SZ + ((e8 ^ (brow & 15)) << 3)];
#pragma unroll
        for (int mt = 0; mt < 2; ++mt) {
            int arow = (mh * 2 + mt) * 32 + l31;
            bf16x8 afr = *(const bf16x8*)&sB[arow * E_SZ + ((e8 ^ (arow & 15)) << 3)];
            acc[mt] = __builtin_amdgcn_mfma_f32_32x32x16_bf16(afr, bfr, acc[mt], 0, 0, 0);
        }
    }

    const float* xqp = x + ((size_t)(b0 + brow) * F_SZ + fq) * E_SZ;
    float sv = 0.f;
#pragma unroll
    for (int mt = 0; mt < 2; ++mt) {
        const int dbase = (mh * 2 + mt) * 32 + hi * 4;
#pragma unroll
        for (int q = 0; q < 4; ++q) {
            float4 xq = *(const float4*)(xqp + dbase + q * 8);
            sv += acc[mt][q * 4 + 0] * xq.x + acc[mt][q * 4 + 1] * xq.y
                + acc[mt][q * 4 + 2] * xq.z + acc[mt][q * 4 + 3] * xq.w;
        }
    }
    sv += __shfl_xor(sv, 32);
    if (hi == 0) red[mh][brow] = sv;
    __syncthreads();

    if (tid < 128)
        out[(size_t)(b0 + tid) * P_SZ + p] = red[0][tid] + red[1][tid];
}

extern "C" void kernel_launch(void* const* d_in, const int* in_sizes, int n_in,
                              void* d_out, int out_size, void* d_ws, size_t ws_size,
                              hipStream_t stream) {
    const float* x    = (const float*)d_in[0];   // [2048, 24, 128] f32
    const float* kern = (const float*)d_in[1];   // [128, 276, 128] f32
    float* out = (float*)d_out;                  // [2048, 276] f32

    if (ws_size >= WS_NEED) {
        __bf16* xft = (__bf16*)d_ws;
        __bf16* kb  = xft + XT_ELEMS;
        prepack_all<<<dim3(XPREP_BLKS + KPREP_BLKS), 256, 0, stream>>>(x, kern, xft, kb);
        opn_main<<<dim3(NWG), 512, 0, stream>>>(xft, kb, out);
    } else {
        opn_fallback<<<dim3(P_SZ * 16), 512, 0, stream>>>(x, kern, out);
    }
}